// Round 1
// baseline (688.736 us; speedup 1.0000x reference)
//
#include <hip/hip_runtime.h>
#include <math.h>

#define D_MODEL 1024
#define N_STATE 64
#define BATCH   16
#define SEQ     1024

__device__ __forceinline__ float sigmoidf_dev(float v) {
    return 1.0f / (1.0f + expf(-v));
}

// ---------------------------------------------------------------------------
// k0: precompute sigmoid(A) [D,N], sigmoid(W_B)^T -> BwT [D,N],
//     sigmoid(W_C) [D,N], sigmoid(gamma) [D]
// ---------------------------------------------------------------------------
__global__ __launch_bounds__(256) void k0_precompute(
        const float* __restrict__ A, const float* __restrict__ W_B,
        const float* __restrict__ W_C, const float* __restrict__ gamma,
        float* __restrict__ A_sig, float* __restrict__ BwT,
        float* __restrict__ Cs, float* __restrict__ gs) {
    int i = blockIdx.x * 256 + threadIdx.x;
    if (i < D_MODEL * N_STATE) {
        A_sig[i] = sigmoidf_dev(A[i]);
        Cs[i]    = sigmoidf_dev(W_C[i]);
        int d = i >> 6, n = i & 63;                 // i = d*64 + n
        BwT[i] = sigmoidf_dev(W_B[n * D_MODEL + d]); // W_B is [N, D]
        if (i < D_MODEL) gs[i] = sigmoidf_dev(gamma[i]);
    }
}

// ---------------------------------------------------------------------------
// k1: bt[m][n] = sum_d x[m][d] * BwT[d][n]   (M=16384, K=1024, N=64, fp32)
// block = 256 threads, Mtile=64, Ntile=64, Ktile=32; 16 outputs/thread (4x4)
// ---------------------------------------------------------------------------
__global__ __launch_bounds__(256) void k1_bt_gemm(
        const float* __restrict__ x, const float* __restrict__ BwT,
        float* __restrict__ bt) {
    __shared__ float xs[32][64 + 1];   // [k][m], +1 pad
    __shared__ float bs[32][64];       // [k][n]

    const int t  = threadIdx.x;
    const int r  = t >> 4;   // 0..15 (m-group)
    const int c  = t & 15;   // 0..15 (n-group)
    const int m0 = blockIdx.x * 64;

    float acc[4][4];
#pragma unroll
    for (int i = 0; i < 4; ++i)
#pragma unroll
        for (int j = 0; j < 4; ++j) acc[i][j] = 0.0f;

    for (int k0 = 0; k0 < D_MODEL; k0 += 32) {
#pragma unroll
        for (int i = 0; i < 8; ++i) {
            int idx = t + i * 256;           // 0..2047
            int mr = idx >> 5, kc = idx & 31;
            xs[kc][mr] = x[(size_t)(m0 + mr) * D_MODEL + k0 + kc];
            int kr = idx >> 6, nc = idx & 63;
            bs[kr][nc] = BwT[(size_t)(k0 + kr) * N_STATE + nc];
        }
        __syncthreads();
#pragma unroll
        for (int kk = 0; kk < 32; ++kk) {
            float a0 = xs[kk][r * 4 + 0];
            float a1 = xs[kk][r * 4 + 1];
            float a2 = xs[kk][r * 4 + 2];
            float a3 = xs[kk][r * 4 + 3];
            float4 bq = *(const float4*)(&bs[kk][c * 4]);
            acc[0][0] = fmaf(a0, bq.x, acc[0][0]);
            acc[0][1] = fmaf(a0, bq.y, acc[0][1]);
            acc[0][2] = fmaf(a0, bq.z, acc[0][2]);
            acc[0][3] = fmaf(a0, bq.w, acc[0][3]);
            acc[1][0] = fmaf(a1, bq.x, acc[1][0]);
            acc[1][1] = fmaf(a1, bq.y, acc[1][1]);
            acc[1][2] = fmaf(a1, bq.z, acc[1][2]);
            acc[1][3] = fmaf(a1, bq.w, acc[1][3]);
            acc[2][0] = fmaf(a2, bq.x, acc[2][0]);
            acc[2][1] = fmaf(a2, bq.y, acc[2][1]);
            acc[2][2] = fmaf(a2, bq.z, acc[2][2]);
            acc[2][3] = fmaf(a2, bq.w, acc[2][3]);
            acc[3][0] = fmaf(a3, bq.x, acc[3][0]);
            acc[3][1] = fmaf(a3, bq.y, acc[3][1]);
            acc[3][2] = fmaf(a3, bq.z, acc[3][2]);
            acc[3][3] = fmaf(a3, bq.w, acc[3][3]);
        }
        __syncthreads();
    }
#pragma unroll
    for (int i = 0; i < 4; ++i) {
        float4 o = make_float4(acc[i][0], acc[i][1], acc[i][2], acc[i][3]);
        *(float4*)(&bt[(size_t)(m0 + r * 4 + i) * N_STATE + c * 4]) = o;
    }
}

// ---------------------------------------------------------------------------
// k2: the sequential scan. 256 blocks x 256 threads.
// block bk: batch b = bk>>4, d-base = (bk&15)*64. Wave w handles 16 d's.
// lane: c = lane&15 -> chain (d), q = lane>>4 -> n in [q*16, q*16+16).
// Each lane holds h[16] in VGPRs. Dot reduced over 4 lanes via shfl_xor,
// pipelined one step behind the h-update to hide shuffle latency.
// Writes y_raw into d_out.
// ---------------------------------------------------------------------------
__global__ __launch_bounds__(256, 1) void k2_scan(
        const float* __restrict__ x, const float* __restrict__ bt,
        const float* __restrict__ A_sig, const float* __restrict__ Cs,
        float* __restrict__ y_raw) {
    const int t    = threadIdx.x;
    const int wave = t >> 6;
    const int lane = t & 63;
    const int c    = lane & 15;
    const int q    = lane >> 4;
    const int b    = blockIdx.x >> 4;
    const int d    = (blockIdx.x & 15) * 64 + wave * 16 + c;

    // constants for this chain (16 n-values each)
    float a[16], cw[16];
    {
        const float* ad = A_sig + (size_t)d * N_STATE + q * 16;
        const float* cd = Cs    + (size_t)d * N_STATE + q * 16;
#pragma unroll
        for (int j = 0; j < 16; j += 4) {
            float4 av = *(const float4*)(ad + j);
            float4 cv = *(const float4*)(cd + j);
            a[j + 0] = av.x; a[j + 1] = av.y; a[j + 2] = av.z; a[j + 3] = av.w;
            cw[j + 0] = cv.x; cw[j + 1] = cv.y; cw[j + 2] = cv.z; cw[j + 3] = cv.w;
        }
    }

    float h[16];
#pragma unroll
    for (int j = 0; j < 16; ++j) h[j] = 0.0f;

    const float* xp   = x     + (size_t)b * SEQ * D_MODEL + d;   // stride D_MODEL per step
    const float* btp  = bt    + (size_t)b * SEQ * N_STATE + q * 16; // stride 64 per step
    float*       yout = y_raw + (size_t)b * SEQ * D_MODEL + d;   // stride D_MODEL per step

    // prefetch step 0
    float  xt_n = xp[0];
    float4 b0n = *(const float4*)(btp + 0);
    float4 b1n = *(const float4*)(btp + 4);
    float4 b2n = *(const float4*)(btp + 8);
    float4 b3n = *(const float4*)(btp + 12);

    float ya_prev = 0.0f;

    for (int s = 0; s < SEQ; ++s) {
        // --- pipelined reduction + store of previous step's partial dot ---
        float r = ya_prev;
        r += __shfl_xor(r, 16);
        r += __shfl_xor(r, 32);
        if (s > 0 && q == 0) yout[(size_t)(s - 1) * D_MODEL] = r;

        const float  xt = xt_n;
        const float4 c0 = b0n, c1 = b1n, c2 = b2n, c3 = b3n;

        // --- prefetch next step ---
        const int sn = s + 1;
        if (sn < SEQ) {
            xt_n = xp[(size_t)sn * D_MODEL];
            const float* bp = btp + (size_t)sn * N_STATE;
            b0n = *(const float4*)(bp + 0);
            b1n = *(const float4*)(bp + 4);
            b2n = *(const float4*)(bp + 8);
            b3n = *(const float4*)(bp + 12);
        }

        float bv[16];
        bv[0] = c0.x; bv[1] = c0.y; bv[2]  = c0.z; bv[3]  = c0.w;
        bv[4] = c1.x; bv[5] = c1.y; bv[6]  = c1.z; bv[7]  = c1.w;
        bv[8] = c2.x; bv[9] = c2.y; bv[10] = c2.z; bv[11] = c2.w;
        bv[12] = c3.x; bv[13] = c3.y; bv[14] = c3.z; bv[15] = c3.w;

        float y0 = 0.f, y1 = 0.f, y2 = 0.f, y3 = 0.f;
#pragma unroll
        for (int j = 0; j < 16; j += 4) {
            float h0 = fminf(fmaxf(fmaf(h[j + 0], a[j + 0], bv[j + 0] * xt), 0.f), 1.f);
            float h1 = fminf(fmaxf(fmaf(h[j + 1], a[j + 1], bv[j + 1] * xt), 0.f), 1.f);
            float h2 = fminf(fmaxf(fmaf(h[j + 2], a[j + 2], bv[j + 2] * xt), 0.f), 1.f);
            float h3 = fminf(fmaxf(fmaf(h[j + 3], a[j + 3], bv[j + 3] * xt), 0.f), 1.f);
            h[j + 0] = h0; h[j + 1] = h1; h[j + 2] = h2; h[j + 3] = h3;
            y0 = fmaf(h0, cw[j + 0], y0);
            y1 = fmaf(h1, cw[j + 1], y1);
            y2 = fmaf(h2, cw[j + 2], y2);
            y3 = fmaf(h3, cw[j + 3], y3);
        }
        ya_prev = (y0 + y1) + (y2 + y3);
    }

    // flush last step
    float r = ya_prev;
    r += __shfl_xor(r, 16);
    r += __shfl_xor(r, 32);
    if (q == 0) yout[(size_t)(SEQ - 1) * D_MODEL] = r;
}

// ---------------------------------------------------------------------------
// k3: per (b,s) row of 1024: two-pass layernorm over d, scale by gs,
//     add residual x, clip to [0,1]. In-place on d_out.
// ---------------------------------------------------------------------------
__global__ __launch_bounds__(256, 1) void k3_norm(
        const float* __restrict__ x, const float* __restrict__ gs,
        float* __restrict__ y) {
    const int row = blockIdx.x;           // b*SEQ + s
    const int t   = threadIdx.x;
    const size_t base = (size_t)row * D_MODEL + t * 4;

    float4 yv = *(const float4*)(y + base);
    float s1 = (yv.x + yv.y) + (yv.z + yv.w);
#pragma unroll
    for (int off = 32; off > 0; off >>= 1) s1 += __shfl_xor(s1, off);

    __shared__ float red[8];
    const int w = t >> 6;
    if ((t & 63) == 0) red[w] = s1;
    __syncthreads();
    const float mu = (red[0] + red[1] + red[2] + red[3]) * (1.0f / (float)D_MODEL);

    const float dx0 = yv.x - mu, dx1 = yv.y - mu, dx2 = yv.z - mu, dx3 = yv.w - mu;
    float s2 = (dx0 * dx0 + dx1 * dx1) + (dx2 * dx2 + dx3 * dx3);
#pragma unroll
    for (int off = 32; off > 0; off >>= 1) s2 += __shfl_xor(s2, off);
    if ((t & 63) == 0) red[4 + w] = s2;
    __syncthreads();
    const float var = (red[4] + red[5] + red[6] + red[7]) * (1.0f / (float)D_MODEL);
    const float rs  = 1.0f / sqrtf(var + 1e-5f);

    float4 gv = *(const float4*)(gs + t * 4);
    float4 xv = *(const float4*)(x + base);
    float4 o;
    o.x = fminf(fmaxf(dx0 * rs * gv.x + xv.x, 0.f), 1.f);
    o.y = fminf(fmaxf(dx1 * rs * gv.y + xv.y, 0.f), 1.f);
    o.z = fminf(fmaxf(dx2 * rs * gv.z + xv.z, 0.f), 1.f);
    o.w = fminf(fmaxf(dx3 * rs * gv.w + xv.w, 0.f), 1.f);
    *(float4*)(y + base) = o;
}

// ---------------------------------------------------------------------------
extern "C" void kernel_launch(void* const* d_in, const int* in_sizes, int n_in,
                              void* d_out, int out_size, void* d_ws, size_t ws_size,
                              hipStream_t stream) {
    (void)in_sizes; (void)n_in; (void)out_size; (void)ws_size;
    const float* x     = (const float*)d_in[0];
    const float* A     = (const float*)d_in[1];
    const float* W_B   = (const float*)d_in[2];
    const float* W_C   = (const float*)d_in[3];
    const float* gamma = (const float*)d_in[4];
    float* out = (float*)d_out;
    float* ws  = (float*)d_ws;

    float* bt    = ws;                                  // 16384*64 = 1048576 floats
    float* A_sig = ws + 1048576;                        // 65536
    float* BwT   = ws + 1048576 + 65536;                // 65536
    float* Cs    = ws + 1048576 + 2 * 65536;            // 65536
    float* gs    = ws + 1048576 + 3 * 65536;            // 1024

    k0_precompute<<<dim3(256), dim3(256), 0, stream>>>(A, W_B, W_C, gamma,
                                                       A_sig, BwT, Cs, gs);
    k1_bt_gemm<<<dim3(256), dim3(256), 0, stream>>>(x, BwT, bt);
    k2_scan<<<dim3(256), dim3(256), 0, stream>>>(x, bt, A_sig, Cs, out);
    k3_norm<<<dim3(BATCH * SEQ), dim3(256), 0, stream>>>(x, gs, out);
}

// Round 2
// 416.721 us; speedup vs baseline: 1.6528x; 1.6528x over previous
//
#include <hip/hip_runtime.h>
#include <math.h>

#define D_MODEL 1024
#define N_STATE 64
#define BATCH   16
#define SEQ     1024
#define CS      32          // scan steps per LDS chunk
#define NCH     (SEQ / CS)  // 32 chunks

__device__ __forceinline__ float sigmoidf_dev(float v) {
    return 1.0f / (1.0f + expf(-v));
}

// ---------------------------------------------------------------------------
// k0: precompute sigmoid(A) [D,N], sigmoid(W_B)^T -> BwT [D,N],
//     sigmoid(W_C) [D,N], sigmoid(gamma) [D]
// ---------------------------------------------------------------------------
__global__ __launch_bounds__(256) void k0_precompute(
        const float* __restrict__ A, const float* __restrict__ W_B,
        const float* __restrict__ W_C, const float* __restrict__ gamma,
        float* __restrict__ A_sig, float* __restrict__ BwT,
        float* __restrict__ Cs, float* __restrict__ gs) {
    int i = blockIdx.x * 256 + threadIdx.x;
    if (i < D_MODEL * N_STATE) {
        A_sig[i] = sigmoidf_dev(A[i]);
        Cs[i]    = sigmoidf_dev(W_C[i]);
        int d = i >> 6, n = i & 63;                  // i = d*64 + n
        BwT[i] = sigmoidf_dev(W_B[n * D_MODEL + d]); // W_B is [N, D]
        if (i < D_MODEL) gs[i] = sigmoidf_dev(gamma[i]);
    }
}

// ---------------------------------------------------------------------------
// k1: bt[m][n] = sum_d x[m][d] * BwT[d][n]  (M=16384, K=1024, N=64, fp32)
// grid 512 (2 blocks/CU), block 256. Mtile=32, Ntile=64, Ktile=32.
// 8 outputs/thread (2m x 4n). Double-buffered LDS + register prefetch.
// ---------------------------------------------------------------------------
__global__ __launch_bounds__(256) void k1_bt_gemm(
        const float* __restrict__ x, const float* __restrict__ BwT,
        float* __restrict__ bt) {
    __shared__ float xs[2][32][34];   // [buf][k][m], +2 pad (8B-aligned pairs)
    __shared__ float bs[2][32][64];   // [buf][k][n]

    const int t  = threadIdx.x;
    const int r  = t >> 4;            // 0..15 -> m rows r*2, r*2+1
    const int c  = t & 15;            // 0..15 -> n quad c*4
    const int m0 = blockIdx.x * 32;

    const int mr  = t >> 3;           // 0..31 (x staging row)
    const int kc4 = (t & 7) * 4;      // 0..28 (x staging k quad)

    float acc[2][4];
#pragma unroll
    for (int i = 0; i < 2; ++i)
#pragma unroll
        for (int j = 0; j < 4; ++j) acc[i][j] = 0.0f;

    // stage chunk 0 into buf 0
    {
        float4 xv = *(const float4*)(x + (size_t)(m0 + mr) * D_MODEL + kc4);
        float4 b0 = *(const float4*)(BwT + t * 4);
        float4 b1 = *(const float4*)(BwT + 1024 + t * 4);
        xs[0][kc4 + 0][mr] = xv.x;
        xs[0][kc4 + 1][mr] = xv.y;
        xs[0][kc4 + 2][mr] = xv.z;
        xs[0][kc4 + 3][mr] = xv.w;
        *(float4*)(&bs[0][0][0] + t * 4)        = b0;
        *(float4*)(&bs[0][0][0] + 1024 + t * 4) = b1;
    }
    __syncthreads();

    for (int kc = 0; kc < 32; ++kc) {
        const int p = kc & 1;
        float4 xv, b0, b1;
        const bool more = (kc + 1 < 32);
        if (more) {
            const int k0 = (kc + 1) * 32;
            xv = *(const float4*)(x + (size_t)(m0 + mr) * D_MODEL + k0 + kc4);
            b0 = *(const float4*)(BwT + (size_t)k0 * N_STATE + t * 4);
            b1 = *(const float4*)(BwT + (size_t)k0 * N_STATE + 1024 + t * 4);
        }
#pragma unroll
        for (int kk = 0; kk < 32; ++kk) {
            float2 ap = *(const float2*)(&xs[p][kk][r * 2]);
            float4 bq = *(const float4*)(&bs[p][kk][c * 4]);
            acc[0][0] = fmaf(ap.x, bq.x, acc[0][0]);
            acc[0][1] = fmaf(ap.x, bq.y, acc[0][1]);
            acc[0][2] = fmaf(ap.x, bq.z, acc[0][2]);
            acc[0][3] = fmaf(ap.x, bq.w, acc[0][3]);
            acc[1][0] = fmaf(ap.y, bq.x, acc[1][0]);
            acc[1][1] = fmaf(ap.y, bq.y, acc[1][1]);
            acc[1][2] = fmaf(ap.y, bq.z, acc[1][2]);
            acc[1][3] = fmaf(ap.y, bq.w, acc[1][3]);
        }
        if (more) {
            const int q = 1 - p;
            xs[q][kc4 + 0][mr] = xv.x;
            xs[q][kc4 + 1][mr] = xv.y;
            xs[q][kc4 + 2][mr] = xv.z;
            xs[q][kc4 + 3][mr] = xv.w;
            *(float4*)(&bs[q][0][0] + t * 4)        = b0;
            *(float4*)(&bs[q][0][0] + 1024 + t * 4) = b1;
        }
        __syncthreads();
    }

#pragma unroll
    for (int i = 0; i < 2; ++i) {
        float4 o = make_float4(acc[i][0], acc[i][1], acc[i][2], acc[i][3]);
        *(float4*)(&bt[(size_t)(m0 + r * 2 + i) * N_STATE + c * 4]) = o;
    }
}

// ---------------------------------------------------------------------------
// k2: sequential scan. grid 1024 (16 batch x 64 d-groups), block 256 (4 waves).
// Block owns 16 chains (d's) of one batch. Lane layout: chain = 16 consecutive
// lanes (cl = wave*4 + lane/16), n-quad nq = lane&15 -> 4 h-states per lane.
// Per-chunk (32 steps) double-buffered LDS staging of bt + x.
// 4-deep software-pipelined shfl_xor(1,2,4,8) reduction (retire lag = 3).
// Writes y_raw into d_out.
// ---------------------------------------------------------------------------
template<bool CHK>
__device__ __forceinline__ void scan_chunk(
        const float* __restrict__ Lb, const float* __restrict__ Lx,
        const int nq, const int cl, const float4 av, const float4 cv,
        float& h0, float& h1, float& h2, float& h3,
        float& pA, float& pB, float& pC, float*& ystore) {
#pragma unroll
    for (int i = 0; i < CS; ++i) {
        const float4 bv = *(const float4*)(Lb + i * 64 + nq * 4);
        const float  xt = Lx[i * 16 + cl];

        // advance the 4-deep reduction pipeline (independent shuffles)
        float outv = pC + __shfl_xor(pC, 8);   // final of step s-3
        pC = pB + __shfl_xor(pB, 4);           // stage3 of s-2
        pB = pA + __shfl_xor(pA, 2);           // stage2 of s-1
        if (!CHK || i >= 3) {
            if (nq == 0) *ystore = outv;
            ystore += D_MODEL;
        }

        // compute step s
        float t0 = fmaf(h0, av.x, bv.x * xt);
        float t1 = fmaf(h1, av.y, bv.y * xt);
        float t2 = fmaf(h2, av.z, bv.z * xt);
        float t3 = fmaf(h3, av.w, bv.w * xt);
        h0 = fminf(fmaxf(t0, 0.f), 1.f);
        h1 = fminf(fmaxf(t1, 0.f), 1.f);
        h2 = fminf(fmaxf(t2, 0.f), 1.f);
        h3 = fminf(fmaxf(t3, 0.f), 1.f);
        float y = fmaf(h0, cv.x, h1 * cv.y) + fmaf(h2, cv.z, h3 * cv.w);
        pA = y + __shfl_xor(y, 1);             // stage1 of s
    }
}

__global__ __launch_bounds__(256, 4) void k2_scan(
        const float* __restrict__ x, const float* __restrict__ bt,
        const float* __restrict__ A_sig, const float* __restrict__ Cs,
        float* __restrict__ y_raw) {
    const int t    = threadIdx.x;
    const int lane = t & 63;
    const int wv   = t >> 6;
    const int nq   = lane & 15;          // n-quad -> n = nq*4
    const int cl   = wv * 4 + (lane >> 4); // chain within block, 0..15
    const int b    = blockIdx.x >> 6;
    const int d0   = (blockIdx.x & 63) * 16;
    const int d    = d0 + cl;

    __shared__ float lbt[2][CS * 64];    // 2 x 8 KB
    __shared__ float lx [2][CS * 16];    // 2 x 2 KB

    const float4 av = *(const float4*)(A_sig + (size_t)d * N_STATE + nq * 4);
    const float4 cv = *(const float4*)(Cs    + (size_t)d * N_STATE + nq * 4);

    float h0 = 0.f, h1 = 0.f, h2 = 0.f, h3 = 0.f;
    float pA = 0.f, pB = 0.f, pC = 0.f;

    const float* btb = bt + (size_t)b * SEQ * N_STATE;
    const float* xb  = x  + (size_t)b * SEQ * D_MODEL + d0;
    float* ystore    = y_raw + (size_t)b * SEQ * D_MODEL + d;  // step-0 slot

    const int xst = t >> 3;          // staging: step 0..31
    const int xdp = (t & 7) * 2;     // staging: d pair

    // stage chunk 0 into buf 0
    {
        float4 b0 = *(const float4*)(btb + t * 4);
        float4 b1 = *(const float4*)(btb + 1024 + t * 4);
        float2 xv = *(const float2*)(xb + (size_t)xst * D_MODEL + xdp);
        *(float4*)(&lbt[0][t * 4])        = b0;
        *(float4*)(&lbt[0][1024 + t * 4]) = b1;
        *(float2*)(&lx[0][xst * 16 + xdp]) = xv;
    }
    __syncthreads();

    for (int ch = 0; ch < NCH; ++ch) {
        const int p = ch & 1;
        float4 n0, n1; float2 nx;
        const bool more = (ch + 1 < NCH);
        if (more) {
            const float* btn = btb + (size_t)(ch + 1) * CS * N_STATE;
            n0 = *(const float4*)(btn + t * 4);
            n1 = *(const float4*)(btn + 1024 + t * 4);
            nx = *(const float2*)(xb + (size_t)((ch + 1) * CS + xst) * D_MODEL + xdp);
        }
        if (ch == 0) {
            scan_chunk<true >(lbt[p], lx[p], nq, cl, av, cv,
                              h0, h1, h2, h3, pA, pB, pC, ystore);
        } else {
            scan_chunk<false>(lbt[p], lx[p], nq, cl, av, cv,
                              h0, h1, h2, h3, pA, pB, pC, ystore);
        }
        if (more) {
            const int q = 1 - p;
            *(float4*)(&lbt[q][t * 4])        = n0;
            *(float4*)(&lbt[q][1024 + t * 4]) = n1;
            *(float2*)(&lx[q][xst * 16 + xdp]) = nx;
        }
        __syncthreads();
    }

    // drain: retire steps SEQ-3, SEQ-2, SEQ-1
    {
        float outv = pC + __shfl_xor(pC, 8);
        if (nq == 0) ystore[0] = outv;
        float c2 = pB + __shfl_xor(pB, 4);
        outv = c2 + __shfl_xor(c2, 8);
        if (nq == 0) ystore[D_MODEL] = outv;
        float b1v = pA + __shfl_xor(pA, 2);
        float c1 = b1v + __shfl_xor(b1v, 4);
        outv = c1 + __shfl_xor(c1, 8);
        if (nq == 0) ystore[2 * D_MODEL] = outv;
    }
}

// ---------------------------------------------------------------------------
// k3: per (b,s) row of 1024: two-pass layernorm over d, scale by gs,
//     add residual x, clip to [0,1]. In-place on d_out.
// ---------------------------------------------------------------------------
__global__ __launch_bounds__(256, 1) void k3_norm(
        const float* __restrict__ x, const float* __restrict__ gs,
        float* __restrict__ y) {
    const int row = blockIdx.x;           // b*SEQ + s
    const int t   = threadIdx.x;
    const size_t base = (size_t)row * D_MODEL + t * 4;

    float4 yv = *(const float4*)(y + base);
    float s1 = (yv.x + yv.y) + (yv.z + yv.w);
#pragma unroll
    for (int off = 32; off > 0; off >>= 1) s1 += __shfl_xor(s1, off);

    __shared__ float red[8];
    const int w = t >> 6;
    if ((t & 63) == 0) red[w] = s1;
    __syncthreads();
    const float mu = (red[0] + red[1] + red[2] + red[3]) * (1.0f / (float)D_MODEL);

    const float dx0 = yv.x - mu, dx1 = yv.y - mu, dx2 = yv.z - mu, dx3 = yv.w - mu;
    float s2 = (dx0 * dx0 + dx1 * dx1) + (dx2 * dx2 + dx3 * dx3);
#pragma unroll
    for (int off = 32; off > 0; off >>= 1) s2 += __shfl_xor(s2, off);
    if ((t & 63) == 0) red[4 + w] = s2;
    __syncthreads();
    const float var = (red[4] + red[5] + red[6] + red[7]) * (1.0f / (float)D_MODEL);
    const float rs  = 1.0f / sqrtf(var + 1e-5f);

    float4 gv = *(const float4*)(gs + t * 4);
    float4 xv = *(const float4*)(x + base);
    float4 o;
    o.x = fminf(fmaxf(dx0 * rs * gv.x + xv.x, 0.f), 1.f);
    o.y = fminf(fmaxf(dx1 * rs * gv.y + xv.y, 0.f), 1.f);
    o.z = fminf(fmaxf(dx2 * rs * gv.z + xv.z, 0.f), 1.f);
    o.w = fminf(fmaxf(dx3 * rs * gv.w + xv.w, 0.f), 1.f);
    *(float4*)(y + base) = o;
}

// ---------------------------------------------------------------------------
extern "C" void kernel_launch(void* const* d_in, const int* in_sizes, int n_in,
                              void* d_out, int out_size, void* d_ws, size_t ws_size,
                              hipStream_t stream) {
    (void)in_sizes; (void)n_in; (void)out_size; (void)ws_size;
    const float* x     = (const float*)d_in[0];
    const float* A     = (const float*)d_in[1];
    const float* W_B   = (const float*)d_in[2];
    const float* W_C   = (const float*)d_in[3];
    const float* gamma = (const float*)d_in[4];
    float* out = (float*)d_out;
    float* ws  = (float*)d_ws;

    float* bt    = ws;                                  // 16384*64 = 1048576 floats
    float* A_sig = ws + 1048576;                        // 65536
    float* BwT   = ws + 1048576 + 65536;                // 65536
    float* Cs    = ws + 1048576 + 2 * 65536;            // 65536
    float* gs    = ws + 1048576 + 3 * 65536;            // 1024

    k0_precompute<<<dim3(256), dim3(256), 0, stream>>>(A, W_B, W_C, gamma,
                                                       A_sig, BwT, Cs, gs);
    k1_bt_gemm<<<dim3(512), dim3(256), 0, stream>>>(x, BwT, bt);
    k2_scan<<<dim3(1024), dim3(256), 0, stream>>>(x, bt, A_sig, Cs, out);
    k3_norm<<<dim3(BATCH * SEQ), dim3(256), 0, stream>>>(x, gs, out);
}

// Round 3
// 413.049 us; speedup vs baseline: 1.6674x; 1.0089x over previous
//
#include <hip/hip_runtime.h>
#include <math.h>

#define D_MODEL 1024
#define N_STATE 64
#define BATCH   16
#define SEQ     1024
#define CS      16          // scan steps per LDS chunk
#define SEGLEN  512         // steps stored per segment
#define WARM    64          // warmup steps for segment 1 (0.7311^64 ~ 2e-9)

__device__ __forceinline__ float sigmoidf_dev(float v) {
    return 1.0f / (1.0f + expf(-v));
}

// ---------------------------------------------------------------------------
// k0: precompute sigmoid(A) [D,N], sigmoid(W_B)^T -> BwT [D,N],
//     sigmoid(W_C) [D,N], sigmoid(gamma) [D]
// ---------------------------------------------------------------------------
__global__ __launch_bounds__(256) void k0_precompute(
        const float* __restrict__ A, const float* __restrict__ W_B,
        const float* __restrict__ W_C, const float* __restrict__ gamma,
        float* __restrict__ A_sig, float* __restrict__ BwT,
        float* __restrict__ Cs, float* __restrict__ gs) {
    int i = blockIdx.x * 256 + threadIdx.x;
    if (i < D_MODEL * N_STATE) {
        A_sig[i] = sigmoidf_dev(A[i]);
        Cs[i]    = sigmoidf_dev(W_C[i]);
        int d = i >> 6, n = i & 63;                  // i = d*64 + n
        BwT[i] = sigmoidf_dev(W_B[n * D_MODEL + d]); // W_B is [N, D]
        if (i < D_MODEL) gs[i] = sigmoidf_dev(gamma[i]);
    }
}

// ---------------------------------------------------------------------------
// k1: bt[m][n] = sum_d x[m][d] * BwT[d][n]  (M=16384, K=1024, N=64, fp32)
// grid 512 (2 blocks/CU), block 256. Mtile=32, Ntile=64, Ktile=32.
// 8 outputs/thread (2m x 4n). Double-buffered LDS + register prefetch.
// ---------------------------------------------------------------------------
__global__ __launch_bounds__(256) void k1_bt_gemm(
        const float* __restrict__ x, const float* __restrict__ BwT,
        float* __restrict__ bt) {
    __shared__ float xs[2][32][34];   // [buf][k][m], +2 pad (8B-aligned pairs)
    __shared__ float bs[2][32][64];   // [buf][k][n]

    const int t  = threadIdx.x;
    const int r  = t >> 4;            // 0..15 -> m rows r*2, r*2+1
    const int c  = t & 15;            // 0..15 -> n quad c*4
    const int m0 = blockIdx.x * 32;

    const int mr  = t >> 3;           // 0..31 (x staging row)
    const int kc4 = (t & 7) * 4;      // 0..28 (x staging k quad)

    float acc[2][4];
#pragma unroll
    for (int i = 0; i < 2; ++i)
#pragma unroll
        for (int j = 0; j < 4; ++j) acc[i][j] = 0.0f;

    // stage chunk 0 into buf 0
    {
        float4 xv = *(const float4*)(x + (size_t)(m0 + mr) * D_MODEL + kc4);
        float4 b0 = *(const float4*)(BwT + t * 4);
        float4 b1 = *(const float4*)(BwT + 1024 + t * 4);
        xs[0][kc4 + 0][mr] = xv.x;
        xs[0][kc4 + 1][mr] = xv.y;
        xs[0][kc4 + 2][mr] = xv.z;
        xs[0][kc4 + 3][mr] = xv.w;
        *(float4*)(&bs[0][0][0] + t * 4)        = b0;
        *(float4*)(&bs[0][0][0] + 1024 + t * 4) = b1;
    }
    __syncthreads();

    for (int kc = 0; kc < 32; ++kc) {
        const int p = kc & 1;
        float4 xv, b0, b1;
        const bool more = (kc + 1 < 32);
        if (more) {
            const int k0 = (kc + 1) * 32;
            xv = *(const float4*)(x + (size_t)(m0 + mr) * D_MODEL + k0 + kc4);
            b0 = *(const float4*)(BwT + (size_t)k0 * N_STATE + t * 4);
            b1 = *(const float4*)(BwT + (size_t)k0 * N_STATE + 1024 + t * 4);
        }
#pragma unroll
        for (int kk = 0; kk < 32; ++kk) {
            float2 ap = *(const float2*)(&xs[p][kk][r * 2]);
            float4 bq = *(const float4*)(&bs[p][kk][c * 4]);
            acc[0][0] = fmaf(ap.x, bq.x, acc[0][0]);
            acc[0][1] = fmaf(ap.x, bq.y, acc[0][1]);
            acc[0][2] = fmaf(ap.x, bq.z, acc[0][2]);
            acc[0][3] = fmaf(ap.x, bq.w, acc[0][3]);
            acc[1][0] = fmaf(ap.y, bq.x, acc[1][0]);
            acc[1][1] = fmaf(ap.y, bq.y, acc[1][1]);
            acc[1][2] = fmaf(ap.y, bq.z, acc[1][2]);
            acc[1][3] = fmaf(ap.y, bq.w, acc[1][3]);
        }
        if (more) {
            const int q = 1 - p;
            xs[q][kc4 + 0][mr] = xv.x;
            xs[q][kc4 + 1][mr] = xv.y;
            xs[q][kc4 + 2][mr] = xv.z;
            xs[q][kc4 + 3][mr] = xv.w;
            *(float4*)(&bs[q][0][0] + t * 4)        = b0;
            *(float4*)(&bs[q][0][0] + 1024 + t * 4) = b1;
        }
        __syncthreads();
    }

#pragma unroll
    for (int i = 0; i < 2; ++i) {
        float4 o = make_float4(acc[i][0], acc[i][1], acc[i][2], acc[i][3]);
        *(float4*)(&bt[(size_t)(m0 + r * 2 + i) * N_STATE + c * 4]) = o;
    }
}

// ---------------------------------------------------------------------------
// k2: sequential scan, time-segmented 2x. grid 2048 = 16 batch x 64 dgroup x
// 2 segments -> 8 blocks/CU, 32 waves/CU (100% occupancy).
// Segment 0: steps [0,512) from h=0 exact. Segment 1: 64 warmup steps
// [448,512) (h-update only; contraction error <= 0.7311^64 ~ 2e-9), then
// stores steps [512,1024).
// Block: 16 chains x 16 lanes; lane holds 4 h-states. CS=16 double-buffered
// LDS staging of bt + x. 4-deep pipelined shfl_xor reduction (retire lag 3).
// ---------------------------------------------------------------------------
__device__ __forceinline__ void warm_chunk(
        const float* __restrict__ Lb, const float* __restrict__ Lx,
        const int nq, const int cl, const float4 av,
        float& h0, float& h1, float& h2, float& h3) {
#pragma unroll
    for (int i = 0; i < CS; ++i) {
        const float4 bv = *(const float4*)(Lb + i * 64 + nq * 4);
        const float  xt = Lx[i * 16 + cl];
        h0 = fminf(fmaxf(fmaf(h0, av.x, bv.x * xt), 0.f), 1.f);
        h1 = fminf(fmaxf(fmaf(h1, av.y, bv.y * xt), 0.f), 1.f);
        h2 = fminf(fmaxf(fmaf(h2, av.z, bv.z * xt), 0.f), 1.f);
        h3 = fminf(fmaxf(fmaf(h3, av.w, bv.w * xt), 0.f), 1.f);
    }
}

template<int SKIP>
__device__ __forceinline__ void main_chunk(
        const float* __restrict__ Lb, const float* __restrict__ Lx,
        const int nq, const int cl, const float4 av, const float4 cv,
        float& h0, float& h1, float& h2, float& h3,
        float& pA, float& pB, float& pC, float*& ystore) {
#pragma unroll
    for (int i = 0; i < CS; ++i) {
        const float4 bv = *(const float4*)(Lb + i * 64 + nq * 4);
        const float  xt = Lx[i * 16 + cl];

        // advance the 4-deep reduction pipeline (independent shuffles)
        float outv = pC + __shfl_xor(pC, 8);   // final of step s-3
        pC = pB + __shfl_xor(pB, 4);           // stage3 of s-2
        pB = pA + __shfl_xor(pA, 2);           // stage2 of s-1
        if (SKIP == 0 || i >= SKIP) {
            if (nq == 0) *ystore = outv;
            ystore += D_MODEL;
        }

        // compute step s
        float t0 = fmaf(h0, av.x, bv.x * xt);
        float t1 = fmaf(h1, av.y, bv.y * xt);
        float t2 = fmaf(h2, av.z, bv.z * xt);
        float t3 = fmaf(h3, av.w, bv.w * xt);
        h0 = fminf(fmaxf(t0, 0.f), 1.f);
        h1 = fminf(fmaxf(t1, 0.f), 1.f);
        h2 = fminf(fmaxf(t2, 0.f), 1.f);
        h3 = fminf(fmaxf(t3, 0.f), 1.f);
        float y = fmaf(h0, cv.x, h1 * cv.y) + fmaf(h2, cv.z, h3 * cv.w);
        pA = y + __shfl_xor(y, 1);             // stage1 of s
    }
}

__global__ __launch_bounds__(256, 8) void k2_scan(
        const float* __restrict__ x, const float* __restrict__ bt,
        const float* __restrict__ A_sig, const float* __restrict__ Cs,
        float* __restrict__ y_raw) {
    const int t    = threadIdx.x;
    const int lane = t & 63;
    const int wv   = t >> 6;
    const int nq   = lane & 15;            // n-quad -> n = nq*4
    const int cl   = wv * 4 + (lane >> 4); // chain within block, 0..15
    const int bid  = blockIdx.x;
    const int seg  = bid & 1;
    const int dg   = (bid >> 1) & 63;
    const int b    = bid >> 7;
    const int d0   = dg * 16;
    const int d    = d0 + cl;

    const int nWarm  = seg ? (WARM / CS) : 0;     // 4 or 0
    const int nTot   = nWarm + (SEGLEN / CS);     // 36 or 32
    const int sStart = seg * SEGLEN - nWarm * CS; // 0 or 448

    __shared__ float lbt[2][CS * 64];    // 2 x 4 KB
    __shared__ float lx [2][CS * 16];    // 2 x 1 KB

    const float4 av = *(const float4*)(A_sig + (size_t)d * N_STATE + nq * 4);
    const float4 cv = *(const float4*)(Cs    + (size_t)d * N_STATE + nq * 4);

    float h0 = 0.f, h1 = 0.f, h2 = 0.f, h3 = 0.f;
    float pA = 0.f, pB = 0.f, pC = 0.f;

    const float* btp = bt + (size_t)b * SEQ * N_STATE + (size_t)sStart * N_STATE;
    const float* xpp = x  + (size_t)b * SEQ * D_MODEL + (size_t)sStart * D_MODEL + d0;
    float* ystore = y_raw + (size_t)b * SEQ * D_MODEL + (size_t)seg * SEGLEN * D_MODEL + d;

    const int xst = t >> 4;          // staging: step 0..15
    const int xdd = t & 15;          // staging: chain

    // stage chunk 0 into buf 0
    {
        float4 b4 = *(const float4*)(btp + t * 4);
        float  xv = xpp[(size_t)xst * D_MODEL + xdd];
        *(float4*)(&lbt[0][t * 4]) = b4;
        lx[0][t] = xv;
    }
    btp += CS * N_STATE;
    xpp += (size_t)CS * D_MODEL;
    __syncthreads();

    for (int ch = 0; ch < nTot; ++ch) {
        const int p = ch & 1;
        float4 nb; float nx;
        const bool more = (ch + 1 < nTot);
        if (more) {
            nb = *(const float4*)(btp + t * 4);
            nx = xpp[(size_t)xst * D_MODEL + xdd];
            btp += CS * N_STATE;
            xpp += (size_t)CS * D_MODEL;
        }
        if (ch < nWarm) {
            warm_chunk(lbt[p], lx[p], nq, cl, av, h0, h1, h2, h3);
        } else if (ch == nWarm) {
            main_chunk<3>(lbt[p], lx[p], nq, cl, av, cv,
                          h0, h1, h2, h3, pA, pB, pC, ystore);
        } else {
            main_chunk<0>(lbt[p], lx[p], nq, cl, av, cv,
                          h0, h1, h2, h3, pA, pB, pC, ystore);
        }
        if (more) {
            const int q = 1 - p;
            *(float4*)(&lbt[q][t * 4]) = nb;
            lx[q][t] = nx;
        }
        __syncthreads();
    }

    // drain: retire the last 3 steps of the segment
    {
        float outv = pC + __shfl_xor(pC, 8);
        if (nq == 0) ystore[0] = outv;
        float c2 = pB + __shfl_xor(pB, 4);
        outv = c2 + __shfl_xor(c2, 8);
        if (nq == 0) ystore[D_MODEL] = outv;
        float b1v = pA + __shfl_xor(pA, 2);
        float c1 = b1v + __shfl_xor(b1v, 4);
        outv = c1 + __shfl_xor(c1, 8);
        if (nq == 0) ystore[2 * D_MODEL] = outv;
    }
}

// ---------------------------------------------------------------------------
// k3: per (b,s) row of 1024: two-pass layernorm over d, scale by gs,
//     add residual x, clip to [0,1]. In-place on d_out.
// ---------------------------------------------------------------------------
__global__ __launch_bounds__(256, 1) void k3_norm(
        const float* __restrict__ x, const float* __restrict__ gs,
        float* __restrict__ y) {
    const int row = blockIdx.x;           // b*SEQ + s
    const int t   = threadIdx.x;
    const size_t base = (size_t)row * D_MODEL + t * 4;

    float4 yv = *(const float4*)(y + base);
    float s1 = (yv.x + yv.y) + (yv.z + yv.w);
#pragma unroll
    for (int off = 32; off > 0; off >>= 1) s1 += __shfl_xor(s1, off);

    __shared__ float red[8];
    const int w = t >> 6;
    if ((t & 63) == 0) red[w] = s1;
    __syncthreads();
    const float mu = (red[0] + red[1] + red[2] + red[3]) * (1.0f / (float)D_MODEL);

    const float dx0 = yv.x - mu, dx1 = yv.y - mu, dx2 = yv.z - mu, dx3 = yv.w - mu;
    float s2 = (dx0 * dx0 + dx1 * dx1) + (dx2 * dx2 + dx3 * dx3);
#pragma unroll
    for (int off = 32; off > 0; off >>= 1) s2 += __shfl_xor(s2, off);
    if ((t & 63) == 0) red[4 + w] = s2;
    __syncthreads();
    const float var = (red[4] + red[5] + red[6] + red[7]) * (1.0f / (float)D_MODEL);
    const float rs  = 1.0f / sqrtf(var + 1e-5f);

    float4 gv = *(const float4*)(gs + t * 4);
    float4 xv = *(const float4*)(x + base);
    float4 o;
    o.x = fminf(fmaxf(dx0 * rs * gv.x + xv.x, 0.f), 1.f);
    o.y = fminf(fmaxf(dx1 * rs * gv.y + xv.y, 0.f), 1.f);
    o.z = fminf(fmaxf(dx2 * rs * gv.z + xv.z, 0.f), 1.f);
    o.w = fminf(fmaxf(dx3 * rs * gv.w + xv.w, 0.f), 1.f);
    *(float4*)(y + base) = o;
}

// ---------------------------------------------------------------------------
extern "C" void kernel_launch(void* const* d_in, const int* in_sizes, int n_in,
                              void* d_out, int out_size, void* d_ws, size_t ws_size,
                              hipStream_t stream) {
    (void)in_sizes; (void)n_in; (void)out_size; (void)ws_size;
    const float* x     = (const float*)d_in[0];
    const float* A     = (const float*)d_in[1];
    const float* W_B   = (const float*)d_in[2];
    const float* W_C   = (const float*)d_in[3];
    const float* gamma = (const float*)d_in[4];
    float* out = (float*)d_out;
    float* ws  = (float*)d_ws;

    float* bt    = ws;                                  // 16384*64 = 1048576 floats
    float* A_sig = ws + 1048576;                        // 65536
    float* BwT   = ws + 1048576 + 65536;                // 65536
    float* Cs    = ws + 1048576 + 2 * 65536;            // 65536
    float* gs    = ws + 1048576 + 3 * 65536;            // 1024

    k0_precompute<<<dim3(256), dim3(256), 0, stream>>>(A, W_B, W_C, gamma,
                                                       A_sig, BwT, Cs, gs);
    k1_bt_gemm<<<dim3(512), dim3(256), 0, stream>>>(x, BwT, bt);
    k2_scan<<<dim3(2048), dim3(256), 0, stream>>>(x, bt, A_sig, Cs, out);
    k3_norm<<<dim3(BATCH * SEQ), dim3(256), 0, stream>>>(x, gs, out);
}